// Round 4
// baseline (147.613 us; speedup 1.0000x reference)
//
#include <hip/hip_runtime.h>
#include <math.h>

// EUNN layer, H=1024: 16 steps of (even + odd) pairwise complex rotations + final phase.
// v8 = single FUSED kernel: v7's LDS double-buffered coeff staging, but coeffs are
// COMPUTED per step (HW sincos) instead of loaded from a precomputed table; the
// separate precompute kernel is gone. Also R=1 (4096 waves -> 4 blocks/CU, 4
// waves/SIMD) now that staging is block-cooperative (extra waves carry no coeff
// re-read overhead, unlike v5).
// Post-mortem history: v5 (R=1, per-wave coeff loads) regressed 52.6->62.4; v6 (NT
// stores) exploded WRITE_SIZE -> reverted; v7 (LDS staging, R=2) = 54.3 ~= v4,
// proving coeff path was NOT the main-loop stall; stall = per-wave dependency
// chain (even -> shfl -> odd) unfillable at 2 waves/SIMD. Separately, bench dur ==
// main dur + ~74us every round -> precompute kernel + inter-kernel gap suspected;
// fusing removes both (and all coeff global traffic).
// Inputs theta/phi are uniform in (-pi,pi], so v_sin/v_cos (revolutions) with one
// multiply is a complete range reduction; error ~1e-7 per coeff, absmax slack ~1e-2.
//
// cbuf slot for pair j: (j&7)*64 + (j>>3)  [+512 for odd phase]
//   -> wave lane l reads pair 8l+p at slot p*64+l (16B/lane contiguous, conflict-free).

typedef float f4 __attribute__((ext_vector_type(4)));
typedef float f2 __attribute__((ext_vector_type(2)));

#define INV_2PI 0.15915494309189535f

__device__ __forceinline__ void hw_sc(float x, float* s, float* c) {
  float r = x * INV_2PI;
  *s = __builtin_amdgcn_sinf(r);
  *c = __builtin_amdgcn_cosf(r);
}

__global__ __launch_bounds__(256, 4) void eunn_fused(
    const float* __restrict__ x, float* __restrict__ out,
    const float* __restrict__ omega, const float* __restrict__ et,
    const float* __restrict__ ot, const float* __restrict__ ep,
    const float* __restrict__ op) {
  __shared__ f4 cbuf[2][1024];  // 2 x 16KB coeff double buffer
  const int tid = threadIdx.x;
  const int lane = tid & 63;
  const int row = blockIdx.x * 4 + (tid >> 6);  // R=1: one row per wave
  const int j0 = 2 * tid;  // this thread stages pairs j0, j0+1 (even AND odd phase)

  // ---- staging split: load (issue early) / commit (sincos + ds_write late) ----
  float let0, let1, lep0, lep1, lot0, lot1, lop0, lop1;
  auto stage_load = [&](int s) {
    f2 a = *(const f2*)(et + s * 512 + j0); let0 = a.x; let1 = a.y;
    f2 b = *(const f2*)(ep + s * 512 + j0); lep0 = b.x; lep1 = b.y;
    const float* otr = ot + s * 511;  // odd rows are length 511 (stride keeps f2
    const float* opr = op + s * 511;  // alignment only for even s -> scalar loads)
    lot0 = otr[j0]; lop0 = opr[j0];
    if (j0 + 1 < 511) { lot1 = otr[j0 + 1]; lop1 = opr[j0 + 1]; }
    else { lot1 = 0.f; lop1 = 0.f; }
  };
  auto stage_commit = [&](int b) {
    float ct, st, cp, sp;
    hw_sc(let0, &st, &ct); hw_sc(lep0, &sp, &cp);
    cbuf[b][(j0 & 7) * 64 + (j0 >> 3)] = (f4){ct, st, cp, sp};
    hw_sc(let1, &st, &ct); hw_sc(lep1, &sp, &cp);
    cbuf[b][((j0 + 1) & 7) * 64 + ((j0 + 1) >> 3)] = (f4){ct, st, cp, sp};
    hw_sc(lot0, &st, &ct); hw_sc(lop0, &sp, &cp);
    cbuf[b][512 + (j0 & 7) * 64 + (j0 >> 3)] = (f4){ct, st, cp, sp};
    if (j0 + 1 < 511) {
      hw_sc(lot1, &st, &ct); hw_sc(lop1, &sp, &cp);
    } else {  // identity pad pair (elements 1023/1024)
      ct = 1.f; st = 0.f; cp = 0.f; sp = 1.f;
    }
    cbuf[b][512 + ((j0 + 1) & 7) * 64 + ((j0 + 1) >> 3)] = (f4){ct, st, cp, sp};
  };

  // ---- prologue: issue step-0 coeff loads, then x loads, then commit ----
  stage_load(0);
  f4 e[8];  // e[p] = (re[16l+2p], im[16l+2p], re[16l+2p+1], im[16l+2p+1])
  {
    const f4* xr = (const f4*)(x + (size_t)row * 2048) + lane * 8;
#pragma unroll
    for (int p = 0; p < 8; ++p) e[p] = xr[p];
  }
  stage_commit(0);
  __syncthreads();

#pragma unroll 1
  for (int s = 0; s < 16; ++s) {
    const int cur = s & 1;
    if (s < 15) stage_load(s + 1);  // global theta/phi loads cover under compute

    f4 E[8], O[8];
#pragma unroll
    for (int p = 0; p < 8; ++p) E[p] = cbuf[cur][p * 64 + lane];
#pragma unroll
    for (int p = 0; p < 8; ++p) O[p] = cbuf[cur][512 + p * 64 + lane];

    // ---- even rotation: pair j=8l+p couples (e.x,e.y) and (e.z,e.w) ----
#pragma unroll
    for (int p = 0; p < 8; ++p) {
      f4 c = E[p];
      f4 v = e[p];
      float t0 = c.x * v.x - c.y * v.z;
      float t1 = c.x * v.y - c.y * v.w;
      e[p] = (f4){c.w * t0 - c.z * t1, c.z * t0 + c.w * t1,
                  c.y * v.x + c.x * v.z, c.y * v.y + c.x * v.w};
    }

    // ---- odd rotation: pair j couples elements 2j+1, 2j+2 ----
    {
      // neighbor pair (8l-1)'s (ct,st) from lane l-1; identity at lane 0
      float ctm = __shfl_up(O[7].x, 1, 64);
      float stm = __shfl_up(O[7].y, 1, 64);
      if (lane == 0) { ctm = 1.f; stm = 0.f; }
      float upx = __shfl_down(e[0].x, 1, 64);  // elem 16l+16 (pre)
      float upy = __shfl_down(e[0].y, 1, 64);
      float dnz = __shfl_up(e[7].z, 1, 64);    // elem 16l-1 (pre)
      float dnw = __shfl_up(e[7].w, 1, 64);
      // element 16l = second half of pair 8l-1
      float nx = stm * dnz + ctm * e[0].x;
      float ny = stm * dnw + ctm * e[0].y;
      e[0].x = nx;
      e[0].y = ny;
      // interior odd pairs j=8l+p, p=0..6
#pragma unroll
      for (int p = 0; p < 7; ++p) {
        f4 c = O[p];
        float e0r = e[p].z, e0i = e[p].w;
        float e1r = e[p + 1].x, e1i = e[p + 1].y;
        float t0 = c.x * e0r - c.y * e1r;
        float t1 = c.x * e0i - c.y * e1i;
        e[p].z = c.w * t0 - c.z * t1;
        e[p].w = c.z * t0 + c.w * t1;
        e[p + 1].x = c.y * e0r + c.x * e1r;
        e[p + 1].y = c.y * e0i + c.x * e1i;
      }
      // boundary pair j=8l+7 (second element lives in lane l+1; lane 63 = identity)
      {
        f4 c = O[7];
        float e0r = e[7].z, e0i = e[7].w;
        float t0 = c.x * e0r - c.y * upx;
        float t1 = c.x * e0i - c.y * upy;
        e[7].z = c.w * t0 - c.z * t1;
        e[7].w = c.z * t0 + c.w * t1;
      }
    }

    // ---- commit next step's coeffs to the other buffer ----
    if (s < 15) {
      stage_commit(cur ^ 1);
      __syncthreads();
    }
  }

  // ---- final diagonal phase (HW sincos on omega) + store ----
  {
    const float* omr = omega + lane * 16;
    f4 og[4];
#pragma unroll
    for (int q = 0; q < 4; ++q) og[q] = *(const f4*)(omr + 4 * q);
    f4* outr = (f4*)(out + (size_t)row * 2048) + lane * 8;
#pragma unroll
    for (int p = 0; p < 8; ++p) {
      float w0 = og[p >> 1][(p & 1) * 2];
      float w1 = og[p >> 1][(p & 1) * 2 + 1];
      float c0, s0, c1, s1;
      hw_sc(w0, &s0, &c0);
      hw_sc(w1, &s1, &c1);
      f4 v = e[p];
      outr[p] = (f4){v.x * c0 - v.y * s0, v.x * s0 + v.y * c0,
                     v.z * c1 - v.w * s1, v.z * s1 + v.w * c1};
    }
  }
}

extern "C" void kernel_launch(void* const* d_in, const int* in_sizes, int n_in,
                              void* d_out, int out_size, void* d_ws, size_t ws_size,
                              hipStream_t stream) {
  const float* x     = (const float*)d_in[0];  // (4096,1024,2)
  const float* omega = (const float*)d_in[1];  // (1024,)
  const float* et    = (const float*)d_in[2];  // (16,512)
  const float* ot    = (const float*)d_in[3];  // (16,511)
  const float* ep    = (const float*)d_in[4];  // (16,512)
  const float* op    = (const float*)d_in[5];  // (16,511)
  float* out = (float*)d_out;

  // Single fused kernel: 4096 rows, 1 row/wave, 4 waves/block -> 1024 blocks
  // (4 blocks/CU, 4 waves/SIMD). Coeffs computed in-kernel; d_ws unused.
  eunn_fused<<<dim3(1024), dim3(256), 0, stream>>>(x, out, omega, et, ot, ep, op);
}

// Round 5
// 134.340 us; speedup vs baseline: 1.0988x; 1.0988x over previous
//
#include <hip/hip_runtime.h>
#include <math.h>

// EUNN layer, H=1024: 16 steps of (even + odd) pairwise complex rotations + final phase.
// v9 = v4 structure (two kernels, transposed coeff table, per-wave global coeff
// prefetch, NO barriers) with R=4 rows/wave (was 2).
// Post-mortem history:
//  v5 (R=1, 2x TLP): VALUBusy 42->51 but dur 52.6->62.4 -> TLP can't fill stalls.
//  v6 (NT stores): WRITE_SIZE 40->102MB (no L2 write merge) -> reverted.
//  v7 (LDS coeff staging): neutral 54.3 -> coeff path is not the stall.
//  v8 (fused sincos): 6.3M LDS bank conflicts (scatter ds_write) + redundant
//      sincos -> 76.8us; but proved bench-main constant (~71us) is harness fixed
//      cost, not precompute (-> keep two-kernel structure).
// Remaining theory: per-wave ILP starvation. VALU issue demand per SIMD is fixed
// (~52K cyc); between serial phase boundaries (even -> shfl -> odd) R=2 exposes
// only 16 independent pair-rotations, and co-resident waves stall on the same
// pattern. R=4 doubles in-wave ILP: 1024 waves (1/SIMD), ~190 VGPR (fits, no
// spill at 256 budget), coeff loads amortized over 2x rows.
//
// ws layout (f4 units): coeff_t[s][phase][512], slot k = (j&7)*64 + (j>>3) for pair j
//   (phase 0 = even pairs 0..511; phase 1 = odd pairs 0..510 + identity pad 511)
// omega (f4 = 2 elements (c,s,c,s)) transposed the same way at float offset 65536.

typedef float f4 __attribute__((ext_vector_type(4)));

#define OMCS_OFF 65536

__global__ __launch_bounds__(256) void eunn_precompute(
    const float* __restrict__ omega, const float* __restrict__ et,
    const float* __restrict__ ot, const float* __restrict__ ep,
    const float* __restrict__ op, float* __restrict__ ws) {
  int tid = blockIdx.x * 256 + threadIdx.x;
  if (tid < 16384) {
    int s = tid >> 10, k = tid & 1023;
    int phase = k >> 9, j = k & 511;
    float ct, st, cp, sp;
    if (phase == 0) {
      sincosf(et[s * 512 + j], &st, &ct);
      sincosf(ep[s * 512 + j], &sp, &cp);
    } else if (j < 511) {
      sincosf(ot[s * 511 + j], &st, &ct);
      sincosf(op[s * 511 + j], &sp, &cp);
    } else {  // identity pad pair (elements 1023/1024)
      ct = 1.f; st = 0.f; cp = 0.f; sp = 1.f;
    }
    // transposed slot: lane = j>>3 owns pair j as its (j&7)-th register
    ((f4*)ws)[s * 1024 + phase * 512 + (j & 7) * 64 + (j >> 3)] =
        (f4){ct, st, cp, sp};
  } else if (tid < 16896) {
    int m = tid - 16384;  // f4 index covering elements 2m, 2m+1
    float s0, c0, s1, c1;
    sincosf(omega[2 * m], &s0, &c0);
    sincosf(omega[2 * m + 1], &s1, &c1);
    ((f4*)(ws + OMCS_OFF))[(m & 7) * 64 + (m >> 3)] = (f4){c0, s0, c1, s1};
  }
}

// One wave owns R rows; lane l owns elements 16l..16l+15 (8 even pairs).
// Even rotations register-local; odd rotations register-local except one
// boundary pair per lane (intra-wave shfl). Pipeline: O loads issue before
// even compute; next step's E loads issue after even compute.
template <int R>
__global__ __launch_bounds__(64, 1) void eunn_main(
    const float* __restrict__ x, float* __restrict__ out,
    const float* __restrict__ ws) {
  const int lane = threadIdx.x & 63;
  const int wid = blockIdx.x;  // one wave per block
  const f4* cf = (const f4*)ws + lane;  // + p*64 + s*1024 (+512 for odd)

  // e[r][p] = (re[16l+2p], im[16l+2p], re[16l+2p+1], im[16l+2p+1])
  f4 e[R][8];
#pragma unroll
  for (int r = 0; r < R; ++r) {
    const f4* xr = (const f4*)(x + (size_t)(wid * R + r) * 2048) + lane * 8;
#pragma unroll
    for (int p = 0; p < 8; ++p) e[r][p] = xr[p];
  }

  f4 E[8];  // current step's even coeffs (ct,st,cp,sp per pair)
#pragma unroll
  for (int p = 0; p < 8; ++p) E[p] = cf[p * 64];

#pragma unroll 1
  for (int s = 0; s < 16; ++s) {
    // ---- issue odd coeff loads (completion covered by even compute) ----
    f4 O[8];
    {
      const f4* ob = cf + s * 1024 + 512;
#pragma unroll
      for (int p = 0; p < 8; ++p) O[p] = ob[p * 64];
    }
    // ---- even rotation: pair j=8l+p couples (e.x,e.y) and (e.z,e.w) ----
#pragma unroll
    for (int r = 0; r < R; ++r) {
#pragma unroll
      for (int p = 0; p < 8; ++p) {
        f4 c = E[p];
        f4 v = e[r][p];
        float t0 = c.x * v.x - c.y * v.z;
        float t1 = c.x * v.y - c.y * v.w;
        e[r][p] = (f4){c.w * t0 - c.z * t1, c.z * t0 + c.w * t1,
                       c.y * v.x + c.x * v.z, c.y * v.y + c.x * v.w};
      }
    }
    // ---- load next step's even coeffs into E (covered by odd compute) ----
    {
      const f4* nb = cf + ((s + 1) & 15) * 1024;
#pragma unroll
      for (int p = 0; p < 8; ++p) E[p] = nb[p * 64];
    }
    // ---- odd rotation: pair j couples elements 2j+1, 2j+2 ----
    {
      // neighbor pair (8l-1)'s (ct,st) from lane l-1; identity at lane 0
      float ctm = __shfl_up(O[7].x, 1, 64);
      float stm = __shfl_up(O[7].y, 1, 64);
      if (lane == 0) { ctm = 1.f; stm = 0.f; }
#pragma unroll
      for (int r = 0; r < R; ++r) {
        float upx = __shfl_down(e[r][0].x, 1, 64);  // elem 16l+16 (pre)
        float upy = __shfl_down(e[r][0].y, 1, 64);
        float dnz = __shfl_up(e[r][7].z, 1, 64);    // elem 16l-1 (pre)
        float dnw = __shfl_up(e[r][7].w, 1, 64);
        // element 16l = second half of pair 8l-1
        float nx = stm * dnz + ctm * e[r][0].x;
        float ny = stm * dnw + ctm * e[r][0].y;
        e[r][0].x = nx;
        e[r][0].y = ny;
        // interior odd pairs j=8l+p, p=0..6
#pragma unroll
        for (int p = 0; p < 7; ++p) {
          f4 c = O[p];
          float e0r = e[r][p].z, e0i = e[r][p].w;
          float e1r = e[r][p + 1].x, e1i = e[r][p + 1].y;
          float t0 = c.x * e0r - c.y * e1r;
          float t1 = c.x * e0i - c.y * e1i;
          e[r][p].z = c.w * t0 - c.z * t1;
          e[r][p].w = c.z * t0 + c.w * t1;
          e[r][p + 1].x = c.y * e0r + c.x * e1r;
          e[r][p + 1].y = c.y * e0i + c.x * e1i;
        }
        // boundary pair j=8l+7 (second element lives in lane l+1; lane 63 = identity)
        {
          f4 c = O[7];
          float e0r = e[r][7].z, e0i = e[r][7].w;
          float t0 = c.x * e0r - c.y * upx;
          float t1 = c.x * e0i - c.y * upy;
          e[r][7].z = c.w * t0 - c.z * t1;
          e[r][7].w = c.z * t0 + c.w * t1;
        }
      }
    }
  }

  // ---- final diagonal phase + store ----
  const f4* om4 = (const f4*)(ws + OMCS_OFF) + lane;  // (c,s,c,s), + p*64
#pragma unroll
  for (int r = 0; r < R; ++r) {
    f4* outr = (f4*)(out + (size_t)(wid * R + r) * 2048) + lane * 8;
#pragma unroll
    for (int p = 0; p < 8; ++p) {
      f4 v = e[r][p];
      f4 w = om4[p * 64];
      outr[p] = (f4){v.x * w.x - v.y * w.y, v.x * w.y + v.y * w.x,
                     v.z * w.z - v.w * w.w, v.z * w.w + v.w * w.z};
    }
  }
}

extern "C" void kernel_launch(void* const* d_in, const int* in_sizes, int n_in,
                              void* d_out, int out_size, void* d_ws, size_t ws_size,
                              hipStream_t stream) {
  const float* x     = (const float*)d_in[0];  // (4096,1024,2)
  const float* omega = (const float*)d_in[1];  // (1024,)
  const float* et    = (const float*)d_in[2];  // (16,512)
  const float* ot    = (const float*)d_in[3];  // (16,511)
  const float* ep    = (const float*)d_in[4];  // (16,512)
  const float* op    = (const float*)d_in[5];  // (16,511)
  float* out = (float*)d_out;
  float* ws  = (float*)d_ws;

  // 16896 jobs: 16x1024 coeff quads + 512 omega f4 entries
  eunn_precompute<<<dim3(66), dim3(256), 0, stream>>>(omega, et, ot, ep, op, ws);

  // R=4 rows/wave: 1024 waves, 1 wave/block -> 1024 blocks (4/CU, 1 wave/SIMD)
  eunn_main<4><<<dim3(1024), dim3(64), 0, stream>>>(x, out, ws);
}

// Round 6
// 116.616 us; speedup vs baseline: 1.2658x; 1.1520x over previous
//
#include <hip/hip_runtime.h>
#include <math.h>

// EUNN layer, H=1024: 16 steps of (even + odd) pairwise complex rotations + final phase.
// v10 = v4 (best, 52.6us: R=2, 512x256 grid, transposed coeff table, per-wave global
// coeff prefetch, no barriers) with the rotation math rewritten as PACKED FP32
// (v_pk_fma_f32 / v_pk_mul_f32 VOP3P inline asm, per-half op_sel/neg modifiers).
// Post-mortem history:
//  v5 (2x TLP): worse.  v6 (NT): WRITE_SIZE 2.5x, worse.  v7 (LDS coeffs): neutral.
//  v8 (fused sincos): LDS write scatter conflicts, worse; proved bench-main ~71us
//      constant is harness fixed cost.  v9 (R=4 ILP): worse, VALUBusy still 42%.
// Model reconciliation: v4 VALUBusy 42% = 53K cyc/SIMD = 26.5K cyc/wave = ~13K VALU
// instr/wave @2cyc == hand count of SCALAR rotation math -> codegen is scalar, and
// VALU issue (~22us) is the largest measured component. Real/imag always get the
// same coefficient multipliers -> the whole rotation is 2-wide packable; packed
// halves VALU issue (12 -> 6 instr/pair). Compiler won't pack on its own.
//
// ws layout (f4 units): coeff_t[s][phase][512], slot k = (j&7)*64 + (j>>3) for pair j
//   (phase 0 = even pairs 0..511; phase 1 = odd pairs 0..510 + identity pad 511)
// omega (f4 = 2 elements (c,s,c,s)) transposed the same way at float offset 65536.

typedef float f4 __attribute__((ext_vector_type(4)));
typedef float f2 __attribute__((ext_vector_type(2)));

#define OMCS_OFF 65536

// ---- packed-f32 rotation primitives (c = (lo,hi) coefficient pair) ----
// T = c.lo*A - c.hi*B   (per half: A/B halves travel together)
__device__ __forceinline__ f2 rot_t(f2 c, f2 A, f2 B) {
  f2 m, t;
  asm("v_pk_mul_f32 %0, %1, %2 op_sel:[1,0] op_sel_hi:[1,1]"
      : "=v"(m) : "v"(c), "v"(B));                      // (hi*B.lo, hi*B.hi)
  asm("v_pk_fma_f32 %0, %1, %2, %3 op_sel:[0,0,0] op_sel_hi:[0,1,1] "
      "neg_lo:[0,0,1] neg_hi:[0,0,1]"
      : "=v"(t) : "v"(c), "v"(A), "v"(m));              // (lo*A.lo-m.lo, lo*A.hi-m.hi)
  return t;
}
// D = (c.hi*T.lo - c.lo*T.hi, c.lo*T.lo + c.hi*T.hi)   [c=(cp,sp), T=(t0,t1)]
__device__ __forceinline__ f2 rot_d(f2 c, f2 T) {
  f2 a, d;
  asm("v_pk_mul_f32 %0, %1, %2 op_sel:[1,0] op_sel_hi:[0,0]"
      : "=v"(a) : "v"(c), "v"(T));                      // (sp*t0, cp*t0)
  asm("v_pk_fma_f32 %0, %1, %2, %3 op_sel:[0,1,0] op_sel_hi:[1,1,1] "
      "neg_lo:[1,0,0] neg_hi:[0,0,0]"
      : "=v"(d) : "v"(c), "v"(T), "v"(a));              // (-cp*t1+a.lo, sp*t1+a.hi)
  return d;
}
// O = c.hi*A + c.lo*B
__device__ __forceinline__ f2 rot_o(f2 c, f2 A, f2 B) {
  f2 m, o;
  asm("v_pk_mul_f32 %0, %1, %2 op_sel:[0,0] op_sel_hi:[0,1]"
      : "=v"(m) : "v"(c), "v"(B));                      // (lo*B.lo, lo*B.hi)
  asm("v_pk_fma_f32 %0, %1, %2, %3 op_sel:[1,0,0] op_sel_hi:[1,1,1]"
      : "=v"(o) : "v"(c), "v"(A), "v"(m));              // (hi*A.lo+m.lo, hi*A.hi+m.hi)
  return o;
}
// complex multiply V*(W.lo + i W.hi): (W.lo*V.lo - W.hi*V.hi, W.hi*V.lo + W.lo*V.hi)
__device__ __forceinline__ f2 cmulp(f2 W, f2 V) {
  f2 m, o;
  asm("v_pk_mul_f32 %0, %1, %2 op_sel:[1,1] op_sel_hi:[1,0]"
      : "=v"(m) : "v"(W), "v"(V));                      // (s*vi, s*vr)
  asm("v_pk_fma_f32 %0, %1, %2, %3 op_sel:[0,0,0] op_sel_hi:[0,1,1] "
      "neg_lo:[0,0,1] neg_hi:[0,0,0]"
      : "=v"(o) : "v"(W), "v"(V), "v"(m));              // (c*vr-m.lo, c*vi+m.hi)
  return o;
}

__global__ __launch_bounds__(256) void eunn_precompute(
    const float* __restrict__ omega, const float* __restrict__ et,
    const float* __restrict__ ot, const float* __restrict__ ep,
    const float* __restrict__ op, float* __restrict__ ws) {
  int tid = blockIdx.x * 256 + threadIdx.x;
  if (tid < 16384) {
    int s = tid >> 10, k = tid & 1023;
    int phase = k >> 9, j = k & 511;
    float ct, st, cp, sp;
    if (phase == 0) {
      sincosf(et[s * 512 + j], &st, &ct);
      sincosf(ep[s * 512 + j], &sp, &cp);
    } else if (j < 511) {
      sincosf(ot[s * 511 + j], &st, &ct);
      sincosf(op[s * 511 + j], &sp, &cp);
    } else {  // identity pad pair (elements 1023/1024)
      ct = 1.f; st = 0.f; cp = 0.f; sp = 1.f;
    }
    // transposed slot: lane = j>>3 owns pair j as its (j&7)-th register
    ((f4*)ws)[s * 1024 + phase * 512 + (j & 7) * 64 + (j >> 3)] =
        (f4){ct, st, cp, sp};
  } else if (tid < 16896) {
    int m = tid - 16384;  // f4 index covering elements 2m, 2m+1
    float s0, c0, s1, c1;
    sincosf(omega[2 * m], &s0, &c0);
    sincosf(omega[2 * m + 1], &s1, &c1);
    ((f4*)(ws + OMCS_OFF))[(m & 7) * 64 + (m >> 3)] = (f4){c0, s0, c1, s1};
  }
}

// One wave owns R rows; lane l owns elements 16l..16l+15 (8 even pairs).
// ea[r][p] = complex element 16l+2p, eb[r][p] = complex element 16l+2p+1 (f2 pairs).
// Even rotations register-local; odd rotations register-local except one
// boundary pair per lane (intra-wave shfl). Pipeline: O loads issue before
// even compute; next step's E loads issue after even compute.
template <int R>
__global__ __launch_bounds__(256, 2) void eunn_main(
    const float* __restrict__ x, float* __restrict__ out,
    const float* __restrict__ ws) {
  const int lane = threadIdx.x & 63;
  const int wid = blockIdx.x * (blockDim.x >> 6) + (threadIdx.x >> 6);
  const f4* cf = (const f4*)ws + lane;  // + p*64 + s*1024 (+512 for odd)

  f2 ea[R][8], eb[R][8];
#pragma unroll
  for (int r = 0; r < R; ++r) {
    const f4* xr = (const f4*)(x + (size_t)(wid * R + r) * 2048) + lane * 8;
#pragma unroll
    for (int p = 0; p < 8; ++p) {
      f4 t = xr[p];
      ea[r][p] = (f2){t.x, t.y};
      eb[r][p] = (f2){t.z, t.w};
    }
  }

  f4 E[8];  // current step's even coeffs (ct,st,cp,sp per pair)
#pragma unroll
  for (int p = 0; p < 8; ++p) E[p] = cf[p * 64];

#pragma unroll 1
  for (int s = 0; s < 16; ++s) {
    // ---- issue odd coeff loads (completion covered by even compute) ----
    f4 O[8];
    {
      const f4* ob = cf + s * 1024 + 512;
#pragma unroll
      for (int p = 0; p < 8; ++p) O[p] = ob[p * 64];
    }
    // ---- even rotation: pair j=8l+p couples ea[p] and eb[p] ----
#pragma unroll
    for (int r = 0; r < R; ++r) {
#pragma unroll
      for (int p = 0; p < 8; ++p) {
        f2 cxy = (f2){E[p].x, E[p].y};   // (ct, st)
        f2 czw = (f2){E[p].z, E[p].w};   // (cp, sp)
        f2 a = ea[r][p], b = eb[r][p];
        f2 T = rot_t(cxy, a, b);         // ct*a - st*b
        ea[r][p] = rot_d(czw, T);        // (sp*t0-cp*t1, cp*t0+sp*t1)
        eb[r][p] = rot_o(cxy, a, b);     // st*a + ct*b
      }
    }
    // ---- load next step's even coeffs into E (covered by odd compute) ----
    {
      const f4* nb = cf + ((s + 1) & 15) * 1024;
#pragma unroll
      for (int p = 0; p < 8; ++p) E[p] = nb[p * 64];
    }
    // ---- odd rotation: pair j couples elements 2j+1, 2j+2 ----
    {
      // neighbor pair (8l-1)'s (ct,st) from lane l-1; identity at lane 0
      float ctm = __shfl_up(O[7].x, 1, 64);
      float stm = __shfl_up(O[7].y, 1, 64);
      if (lane == 0) { ctm = 1.f; stm = 0.f; }
      f2 cm2 = (f2){ctm, stm};
#pragma unroll
      for (int r = 0; r < R; ++r) {
        float upx = __shfl_down(ea[r][0].x, 1, 64);  // elem 16l+16 (pre)
        float upy = __shfl_down(ea[r][0].y, 1, 64);
        float dnz = __shfl_up(eb[r][7].x, 1, 64);    // elem 16l-1 (pre)
        float dnw = __shfl_up(eb[r][7].y, 1, 64);
        // element 16l = second half of pair 8l-1: stm*D + ctm*X
        f2 D = (f2){dnz, dnw};
        ea[r][0] = rot_o(cm2, D, ea[r][0]);
        // interior odd pairs j=8l+p, p=0..6: couples eb[p] and ea[p+1]
#pragma unroll
        for (int p = 0; p < 7; ++p) {
          f2 oxy = (f2){O[p].x, O[p].y};
          f2 ozw = (f2){O[p].z, O[p].w};
          f2 A = eb[r][p], B = ea[r][p + 1];
          f2 T = rot_t(oxy, A, B);
          eb[r][p] = rot_d(ozw, T);
          ea[r][p + 1] = rot_o(oxy, A, B);
        }
        // boundary pair j=8l+7 (second element lives in lane l+1; lane 63 = identity)
        {
          f2 oxy = (f2){O[7].x, O[7].y};
          f2 ozw = (f2){O[7].z, O[7].w};
          f2 UP = (f2){upx, upy};
          f2 T = rot_t(oxy, eb[r][7], UP);
          eb[r][7] = rot_d(ozw, T);
        }
      }
    }
  }

  // ---- final diagonal phase + store ----
  const f4* om4 = (const f4*)(ws + OMCS_OFF) + lane;  // (c,s,c,s), + p*64
#pragma unroll
  for (int r = 0; r < R; ++r) {
    f4* outr = (f4*)(out + (size_t)(wid * R + r) * 2048) + lane * 8;
#pragma unroll
    for (int p = 0; p < 8; ++p) {
      f4 w = om4[p * 64];
      f2 o1 = cmulp((f2){w.x, w.y}, ea[r][p]);
      f2 o2 = cmulp((f2){w.z, w.w}, eb[r][p]);
      outr[p] = (f4){o1.x, o1.y, o2.x, o2.y};
    }
  }
}

extern "C" void kernel_launch(void* const* d_in, const int* in_sizes, int n_in,
                              void* d_out, int out_size, void* d_ws, size_t ws_size,
                              hipStream_t stream) {
  const float* x     = (const float*)d_in[0];  // (4096,1024,2)
  const float* omega = (const float*)d_in[1];  // (1024,)
  const float* et    = (const float*)d_in[2];  // (16,512)
  const float* ot    = (const float*)d_in[3];  // (16,511)
  const float* ep    = (const float*)d_in[4];  // (16,512)
  const float* op    = (const float*)d_in[5];  // (16,511)
  float* out = (float*)d_out;
  float* ws  = (float*)d_ws;

  // 16896 jobs: 16x1024 coeff quads + 512 omega f4 entries
  eunn_precompute<<<dim3(66), dim3(256), 0, stream>>>(omega, et, ot, ep, op, ws);

  // R=2 rows/wave: 2048 waves, 4 waves/block -> 512 blocks (2/CU, 8 waves/CU)
  eunn_main<2><<<dim3(512), dim3(256), 0, stream>>>(x, out, ws);
}